// Round 8
// baseline (569.048 us; speedup 1.0000x reference)
//
#include <hip/hip_runtime.h>
#include <cstdint>
#include <cstddef>

// MossVLSelfAttention fused pipeline, MI355X round 8.
// Change vs round 7 (ONE experiment, k_flash only): T14 async-STAGE split.
// Round 7 showed flash == round 4 (137us) despite 2x occupancy: per-tile
// serial chain dominated by stage->syncthreads vmcnt(0) drain (~700cy
// exposed/tile). Now: global->REG loads for tile kt+1 issued BEFORE compute(kt)
// (latency hides under ~1500cy compute), reg->LDS ds_write AFTER the barrier.
// Same bytes, same swizzle involution, same global addresses. Plus setprio(1)
// around MFMA clusters (m191: multi-block attn +4-7%).
// GEMMs/merge/splits unchanged (isolate the experiment).
// Precision: bf16x3 matmuls, fp32 softmax/accum, bf16x2 partial-O.
// Workspace (byte offsets, ~146 MB): same as round 7.

#define C_NH 16
#define C_NKV 8
#define C_DH 128
#define C_HID 2048
#define C_NQKV 4096
#define KVB 32

typedef unsigned short u16;
typedef __attribute__((ext_vector_type(8))) short short8;
typedef __attribute__((ext_vector_type(4))) float f32x4;

__device__ __forceinline__ u16 f2bf(float x) {
  uint32_t u = __float_as_uint(x);
  u += 0x7FFFu + ((u >> 16) & 1u);   // round-to-nearest-even
  return (u16)(u >> 16);
}
__device__ __forceinline__ float bf2f(u16 h) {
  return __uint_as_float(((uint32_t)h) << 16);
}
__device__ __forceinline__ void bsplit(float x, u16& hi, u16& lo) {
  u16 h = f2bf(x);
  hi = h;
  lo = f2bf(x - bf2f(h));             // residual: ~16 mantissa bits total
}

// async global->LDS, 16B/lane; LDS dest = wave-uniform base + lane*16.
__device__ __forceinline__ void gload16(const void* g, void* l) {
  __builtin_amdgcn_global_load_lds(
      (const __attribute__((address_space(1))) void*)g,
      (__attribute__((address_space(3))) void*)l, 16, 0, 0);
}

// ---------------- trig table ---------------------------------------------------
__global__ void k_trig(const int* __restrict__ pos, float2* __restrict__ tab) {
  int t = blockIdx.x;
  int j = threadIdx.x;                // 64 threads
  float inv = 1.0f / powf(1.0e6f, (float)j * (1.0f / 64.0f));
  float ang = (float)pos[t] * inv;
  tab[t * 64 + j] = make_float2(cosf(ang), sinf(ang));
}

// ---------------- plain split: f32[n] -> hi/lo bf16 ---------------------------
struct __align__(8) U4 { u16 a, b, c, d; };

__global__ void k_split(const float* __restrict__ in, u16* __restrict__ hi,
                        u16* __restrict__ lo, int n) {
  int i = (blockIdx.x * 256 + threadIdx.x) * 4;
  if (i >= n) return;
  float4 x = *(const float4*)(in + i);
  U4 hv, lv;
  bsplit(x.x, hv.a, lv.a);
  bsplit(x.y, hv.b, lv.b);
  bsplit(x.z, hv.c, lv.c);
  bsplit(x.w, hv.d, lv.d);
  *(U4*)(hi + i) = hv;
  *(U4*)(lo + i) = lv;
}

// ---------------- split + transpose: in[K][N] -> hi/lo[N][K] ------------------
__global__ void k_split_tr(const float* __restrict__ in, u16* __restrict__ hi,
                           u16* __restrict__ lo, int K, int N) {
  __shared__ float t[64][65];
  const int kb = blockIdx.y * 64, nb = blockIdx.x * 64;
  const int tid = threadIdx.x;
  for (int i = tid; i < 4096; i += 256) {
    int r = i >> 6, c = i & 63;
    t[r][c] = in[(size_t)(kb + r) * N + nb + c];
  }
  __syncthreads();
  for (int i = tid; i < 4096; i += 256) {
    int r = i >> 6, c = i & 63;       // r = n-local, c = k-local
    u16 h, l;
    bsplit(t[c][r], h, l);
    size_t o = (size_t)(nb + r) * K + kb + c;
    hi[o] = h;
    lo[o] = l;
  }
}

// ---------------- bf16x3 GEMM: C[M][N] = A[M][K] * B^T[N][K] ------------------
// m97 structure: 128x128 tile, 4 waves, BK=32, single-buffer LDS staged via
// global_load_lds width=16, 2 barriers per K-step. Plain stores.
__global__ __launch_bounds__(256, 2)
void k_gemm_x3(const u16* __restrict__ Ah, const u16* __restrict__ Al,
               const u16* __restrict__ Bh, const u16* __restrict__ Bl,
               float* __restrict__ C, int M, int N, int K) {
  __shared__ u16 lds[4][4096];          // [Ah,Al,Bh,Bl][128 rows x 32 k]
  const int tid = threadIdx.x;
  const int lane = tid & 63;
  const int wv = tid >> 6;
  const int wr = wv >> 1, wc = wv & 1;
  const int mb = blockIdx.y * 128, nb = blockIdx.x * 128;
  const int ra = lane & 15, ko = (lane >> 4) * 8;

  f32x4 acc[4][4] = {};
  const int nk = K >> 5;
  const int rS = lane >> 2, cS = (lane & 3) * 8;   // staging row/col in chunk

  for (int kt = 0; kt < nk; ++kt) {
    const int kb = kt * 32;
    __syncthreads();                    // previous compute done, LDS reusable
#pragma unroll
    for (int ci = 0; ci < 2; ++ci) {    // wave stages chunks 2w, 2w+1 (16 rows)
      int c = wv * 2 + ci;
      int row = c * 16 + rS;
      gload16(Ah + (size_t)(mb + row) * K + kb + cS, &lds[0][c * 512]);
      gload16(Al + (size_t)(mb + row) * K + kb + cS, &lds[1][c * 512]);
      gload16(Bh + (size_t)(nb + row) * K + kb + cS, &lds[2][c * 512]);
      gload16(Bl + (size_t)(nb + row) * K + kb + cS, &lds[3][c * 512]);
    }
    __syncthreads();                    // drains vmcnt before barrier

    short8 a_h[4], a_l[4], b_h[4], b_l[4];
#pragma unroll
    for (int m = 0; m < 4; ++m) {
      int r = (wr * 64 + m * 16 + ra) * 32 + ko;
      a_h[m] = *(const short8*)&lds[0][r];
      a_l[m] = *(const short8*)&lds[1][r];
    }
#pragma unroll
    for (int n = 0; n < 4; ++n) {
      int r = (wc * 64 + n * 16 + ra) * 32 + ko;
      b_h[n] = *(const short8*)&lds[2][r];
      b_l[n] = *(const short8*)&lds[3][r];
    }
#pragma unroll
    for (int m = 0; m < 4; ++m)
#pragma unroll
      for (int n = 0; n < 4; ++n) {
        acc[m][n] = __builtin_amdgcn_mfma_f32_16x16x32_bf16(a_h[m], b_h[n], acc[m][n], 0, 0, 0);
        acc[m][n] = __builtin_amdgcn_mfma_f32_16x16x32_bf16(a_h[m], b_l[n], acc[m][n], 0, 0, 0);
        acc[m][n] = __builtin_amdgcn_mfma_f32_16x16x32_bf16(a_l[m], b_h[n], acc[m][n], 0, 0, 0);
      }
  }
  const int cr = mb + wr * 64 + (lane >> 4) * 4;
  const int cc = nb + wc * 64 + ra;
#pragma unroll
  for (int m = 0; m < 4; ++m)
#pragma unroll
    for (int n = 0; n < 4; ++n)
#pragma unroll
      for (int r = 0; r < 4; ++r)
        C[(size_t)(cr + m * 16 + r) * N + cc + n * 16] = acc[m][n][r];
}

// ---------------- RMSNorm + RoPE + split (q,k) / split+transpose (v) ----------
__global__ void k_normrope(const float* __restrict__ qkv, const float2* __restrict__ tab,
                           const float* __restrict__ qw, const float* __restrict__ kw,
                           u16* __restrict__ Qh, u16* __restrict__ Ql,
                           u16* __restrict__ Kh, u16* __restrict__ Kl,
                           u16* __restrict__ Vh, u16* __restrict__ Vl, int T) {
  int gw = blockIdx.x * 4 + (threadIdx.x >> 6);
  if (gw >= T * 32) return;
  int lane = threadIdx.x & 63;
  int t = gw >> 5, hd = gw & 31;
  const float* src;
  if (hd < C_NH)              src = qkv + (size_t)t * C_NQKV + hd * C_DH;
  else if (hd < C_NH + C_NKV) src = qkv + (size_t)t * C_NQKV + C_NH * C_DH + (hd - C_NH) * C_DH;
  else                        src = qkv + (size_t)t * C_NQKV + (C_NH + C_NKV) * C_DH + (hd - C_NH - C_NKV) * C_DH;
  float x1 = src[lane], x2 = src[lane + 64];

  if (hd >= C_NH + C_NKV) {   // v: split + store transposed [8][128][T]
    int vh = hd - C_NH - C_NKV;
    u16 h, l;
    bsplit(x1, h, l);
    size_t o1 = ((size_t)vh * C_DH + lane) * T + t;
    Vh[o1] = h; Vl[o1] = l;
    bsplit(x2, h, l);
    size_t o2 = ((size_t)vh * C_DH + lane + 64) * T + t;
    Vh[o2] = h; Vl[o2] = l;
    return;
  }
  float ss = x1 * x1 + x2 * x2;
  ss += __shfl_xor(ss, 1, 64);
  ss += __shfl_xor(ss, 2, 64);
  ss += __shfl_xor(ss, 4, 64);
  ss += __shfl_xor(ss, 8, 64);
  ss += __shfl_xor(ss, 16, 64);
  ss += __shfl_xor(ss, 32, 64);
  float rms = rsqrtf(ss * (1.0f / 128.0f) + 1e-6f);
  const float* w = (hd < C_NH) ? qw : kw;
  float y1 = x1 * rms * w[lane];
  float y2 = x2 * rms * w[lane + 64];
  float2 cs = tab[t * 64 + lane];
  float o1 = y1 * cs.x - y2 * cs.y;
  float o2 = y2 * cs.x + y1 * cs.y;
  u16 h, l;
  if (hd < C_NH) {
    size_t o = ((size_t)t * C_NH + hd) * C_DH + lane;
    bsplit(o1, h, l); Qh[o] = h; Ql[o] = l;
    bsplit(o2, h, l); Qh[o + 64] = h; Ql[o + 64] = l;
  } else {
    int kh = hd - C_NH;
    size_t o = ((size_t)t * C_NKV + kh) * C_DH + lane;
    bsplit(o1, h, l); Kh[o] = h; Kl[o] = l;
    bsplit(o2, h, l); Kh[o + 64] = h; Kl[o + 64] = l;
  }
}

// ---------------- causal flash attention v7 (T14 async-stage, key-split x3) ---
// Grid 768: hk = f&7 (XCD pin), qt = (f>>3)&31, ks = f>>8 in {0,1,2}.
// Block 512 thr / 8 waves; wave owns 16 q-rows of one of 2 GQA heads.
// KVB=32 single LDS buffer; per tile: loads for kt+1 issued to REGS before
// compute(kt) (HBM latency hides under MFMA/softmax), barrier, ds_write regs
// into KV, barrier. Same swizzle involution as round 7 (global pre-swizzled).
__global__ __launch_bounds__(512, 4)
void k_flash(const u16* __restrict__ Qh, const u16* __restrict__ Ql,
             const u16* __restrict__ Kg_h, const u16* __restrict__ Kg_l,
             const u16* __restrict__ Vg_h, const u16* __restrict__ Vg_l,
             u16* __restrict__ Oph, u16* __restrict__ Opl,
             float* __restrict__ Mp, float* __restrict__ Lp, int T) {
  __shared__ u16 KV[4][KVB * C_DH];      // [Kh,Kl,Vh,Vl] 32x128 each = 32 KiB
  __shared__ u16 Pex[8][2][16 * 36];     // per-wave P hi/lo, pad 36 = 18 KiB
  const int tid = threadIdx.x, lane = tid & 63, wv = tid >> 6;
  const int lm = lane & 15, lq = lane >> 4;
  const int f = blockIdx.x;
  const int hk = f & 7, qt = (f >> 3) & 31, ks = f >> 8;
  const int wq = wv & 3, wh = wv >> 2;
  const int h = hk * 2 + wh;
  const int row16 = qt * 64 + wq * 16;      // wave's 16-row base (global)

  // ---- Q fragments in registers for the whole kernel ----
  short8 qfh[4], qfl[4];
#pragma unroll
  for (int kc = 0; kc < 4; ++kc) {
    size_t o = ((size_t)(row16 + lm) * C_NH + h) * C_DH + kc * 32 + lq * 8;
    qfh[kc] = *(const short8*)(Qh + o);
    qfl[kc] = *(const short8*)(Ql + o);
  }
  f32x4 o_acc[8] = {};
  float m_r[4], l_r[4];
#pragma unroll
  for (int r = 0; r < 4; ++r) { m_r[r] = -1e30f; l_r[r] = 0.f; }

  // ---- T14 staging: wave (wv>>1) owns array, (wv&1) owns 16-row half ----
  // load_regs(kt): 4x global_load_dwordx4 -> stg (issued EARLY, before compute)
  // write_lds(): after barrier, ds_write_b128 stg into KV (vmcnt wait is here)
  const int s_arr = wv >> 1, s_hf = wv & 1;
  const int s_rr = lane >> 4, s_ph = lane & 15;
  short8 stg[4];
  auto load_regs = [&](int kt) {
    const int kvb = kt * KVB;
#pragma unroll
    for (int j = 0; j < 4; ++j) {
      const int r0 = s_hf * 16 + j * 4;
      const int r = r0 + s_rr;
      const int c = s_ph ^ (r & 15);          // logical chunk (pre-swizzled src)
      const u16* g;
      if (s_arr < 2) {                         // K: [key][128] rows
        const u16* base = (s_arr == 0) ? Kg_h : Kg_l;
        g = base + ((size_t)(kvb + r) * C_NKV + hk) * C_DH + c * 8;
      } else {                                 // V: logical (r=d&31, c=(d>>5)*4+keychunk)
        const int d = r + ((c >> 2) << 5);
        const u16* base = (s_arr == 2) ? Vg_h : Vg_l;
        g = base + ((size_t)hk * C_DH + d) * T + kvb + (c & 3) * 8;
      }
      stg[j] = *(const short8*)g;
    }
  };
  auto write_lds = [&]() {
#pragma unroll
    for (int j = 0; j < 4; ++j) {
      const int r0 = s_hf * 16 + j * 4;
      // same dest bytes gload16 wrote: wave base &KV[s_arr][r0*128] + lane*16B
      *(short8*)&KV[s_arr][r0 * C_DH + lane * 8] = stg[j];
    }
  };

  const float scale = 0.08838834764831845f;   // 1/sqrt(128)
  const int nt32 = 2 * qt + 2;
  const int t0 = (ks * nt32) / 3, t1 = ((ks + 1) * nt32) / 3;

  load_regs(t0);
  write_lds();
  __syncthreads();                            // tile t0 visible

  for (int kt = t0; kt < t1; ++kt) {
    const int kvb = kt * KVB;
    if (kt + 1 < t1) load_regs(kt + 1);       // issue early: hides under compute

    // ---- S = Q K^T (swizzled LDS reads) ----
    f32x4 s[2] = {};
    __builtin_amdgcn_s_setprio(1);
#pragma unroll
    for (int nt = 0; nt < 2; ++nt) {
      const int krow = nt * 16 + lm;
#pragma unroll
      for (int kc = 0; kc < 4; ++kc) {
        const int phys = (kc * 4 + lq) ^ lm;       // (row&15)==lm
        short8 bh = *(const short8*)&KV[0][krow * C_DH + phys * 8];
        short8 bl = *(const short8*)&KV[1][krow * C_DH + phys * 8];
        s[nt] = __builtin_amdgcn_mfma_f32_16x16x32_bf16(qfh[kc], bh, s[nt], 0, 0, 0);
        s[nt] = __builtin_amdgcn_mfma_f32_16x16x32_bf16(qfh[kc], bl, s[nt], 0, 0, 0);
        s[nt] = __builtin_amdgcn_mfma_f32_16x16x32_bf16(qfl[kc], bh, s[nt], 0, 0, 0);
      }
    }
    __builtin_amdgcn_s_setprio(0);

    // ---- online softmax; `safe` guards fully-masked-first-tile (m=-1e30) ----
    float p[2][4];                                  // [nt][r]
#pragma unroll
    for (int r = 0; r < 4; ++r) {
      const int qrow = row16 + lq * 4 + r;
      float sv[2];
#pragma unroll
      for (int nt = 0; nt < 2; ++nt)
        sv[nt] = (kvb + nt * 16 + lm <= qrow) ? s[nt][r] * scale : -1e30f;
      float pm = fmaxf(sv[0], sv[1]);
      pm = fmaxf(pm, __shfl_xor(pm, 1, 16));
      pm = fmaxf(pm, __shfl_xor(pm, 2, 16));
      pm = fmaxf(pm, __shfl_xor(pm, 4, 16));
      pm = fmaxf(pm, __shfl_xor(pm, 8, 16));
      float mn = fmaxf(m_r[r], pm);
      const float safe = (mn <= -1e29f) ? 0.f : 1.f;
      float alpha = __expf(m_r[r] - mn);
      float ps = 0.f;
#pragma unroll
      for (int nt = 0; nt < 2; ++nt) {
        p[nt][r] = safe * __expf(sv[nt] - mn);
        ps += p[nt][r];
      }
      ps += __shfl_xor(ps, 1, 16);
      ps += __shfl_xor(ps, 2, 16);
      ps += __shfl_xor(ps, 4, 16);
      ps += __shfl_xor(ps, 8, 16);
      l_r[r] = l_r[r] * alpha + ps;
      m_r[r] = mn;
#pragma unroll
      for (int jb = 0; jb < 8; ++jb) o_acc[jb][r] *= alpha;
    }

    // ---- O += P V (K=32 over the whole tile; wave-local P exchange) ----
#pragma unroll
    for (int r = 0; r < 4; ++r)
#pragma unroll
      for (int t2 = 0; t2 < 2; ++t2) {
        u16 ph, pl;
        bsplit(p[t2][r], ph, pl);
        Pex[wv][0][(lq * 4 + r) * 36 + t2 * 16 + lm] = ph;
        Pex[wv][1][(lq * 4 + r) * 36 + t2 * 16 + lm] = pl;
      }
    short8 pah = *(const short8*)&Pex[wv][0][lm * 36 + lq * 8];
    short8 pal = *(const short8*)&Pex[wv][1][lm * 36 + lq * 8];
    __builtin_amdgcn_s_setprio(1);
#pragma unroll
    for (int jb = 0; jb < 8; ++jb) {
      const int vrow = (jb & 1) * 16 + lm;               // = d & 31
      const int phys = ((jb >> 1) * 4 + lq) ^ lm;        // chunk ^ (row&15)
      const int roff = vrow * C_DH + phys * 8;
      short8 vh = *(const short8*)&KV[2][roff];
      short8 vl = *(const short8*)&KV[3][roff];
      o_acc[jb] = __builtin_amdgcn_mfma_f32_16x16x32_bf16(pah, vh, o_acc[jb], 0, 0, 0);
      o_acc[jb] = __builtin_amdgcn_mfma_f32_16x16x32_bf16(pah, vl, o_acc[jb], 0, 0, 0);
      o_acc[jb] = __builtin_amdgcn_mfma_f32_16x16x32_bf16(pal, vh, o_acc[jb], 0, 0, 0);
    }
    __builtin_amdgcn_s_setprio(0);
    __syncthreads();                          // all waves done reading KV[kt]
    if (kt + 1 < t1) write_lds();             // vmcnt wait lands HERE (hidden)
    __syncthreads();                          // tile kt+1 visible
  }

  // ---- partial write: unnormalized O (bf16 hi/lo) + per-row stats ----
  const int S = T * C_NH;
#pragma unroll
  for (int r = 0; r < 4; ++r) {
    const int qrow = row16 + lq * 4 + r;
    const int rh = qrow * C_NH + h;
    if (lm == 0) { Mp[ks * S + rh] = m_r[r]; Lp[ks * S + rh] = l_r[r]; }
#pragma unroll
    for (int jb = 0; jb < 8; ++jb) {
      u16 hh, ll;
      bsplit(o_acc[jb][r], hh, ll);
      size_t oo = ((size_t)ks * S + rh) * C_DH + jb * 16 + lm;
      Oph[oo] = hh;
      Opl[oo] = ll;
    }
  }
}

// ---------------- merge 3 key-split partials -> bf16 hi/lo attn ---------------
__global__ void k_merge(const u16* __restrict__ Oph, const u16* __restrict__ Opl,
                        const float* __restrict__ Mp, const float* __restrict__ Lp,
                        u16* __restrict__ Oh, u16* __restrict__ Ol, int T) {
  const int idx = blockIdx.x * 256 + threadIdx.x;   // T*NH*16 total
  const int rh = idx >> 4, dg = idx & 15;
  const int S = T * C_NH;
  float m0 = Mp[rh], m1 = Mp[S + rh], m2 = Mp[2 * S + rh];
  float M = fmaxf(fmaxf(m0, m1), m2);
  float w0 = __expf(m0 - M), w1 = __expf(m1 - M), w2 = __expf(m2 - M);
  float L = w0 * Lp[rh] + w1 * Lp[S + rh] + w2 * Lp[2 * S + rh];
  float inv = 1.0f / L;
  const size_t b = (size_t)rh * C_DH + dg * 8;
  const size_t SO = (size_t)S * C_DH;
  short8 h0 = *(const short8*)(Oph + b),      l0 = *(const short8*)(Opl + b);
  short8 h1 = *(const short8*)(Oph + SO + b), l1 = *(const short8*)(Opl + SO + b);
  short8 h2 = *(const short8*)(Oph + 2 * SO + b), l2 = *(const short8*)(Opl + 2 * SO + b);
  short8 oh, ol;
#pragma unroll
  for (int j = 0; j < 8; ++j) {
    float o = w0 * (bf2f((u16)h0[j]) + bf2f((u16)l0[j]))
            + w1 * (bf2f((u16)h1[j]) + bf2f((u16)l1[j]))
            + w2 * (bf2f((u16)h2[j]) + bf2f((u16)l2[j]));
    u16 hh, ll;
    bsplit(o * inv, hh, ll);
    oh[j] = (short)hh;
    ol[j] = (short)ll;
  }
  *(short8*)(Oh + b) = oh;
  *(short8*)(Ol + b) = ol;
}

// ---------------- launch --------------------------------------------------------
extern "C" void kernel_launch(void* const* d_in, const int* in_sizes, int n_in,
                              void* d_out, int out_size, void* d_ws, size_t ws_size,
                              hipStream_t stream) {
  const int*   pos  = (const int*)d_in[0];
  const float* hid  = (const float*)d_in[1];
  const float* wqkv = (const float*)d_in[2];
  const float* qnw  = (const float*)d_in[3];
  const float* knw  = (const float*)d_in[4];
  const float* wo   = (const float*)d_in[5];
  float* out = (float*)d_out;
  const int T = in_sizes[0];                   // 2048

  char* ws = (char*)d_ws;
  const size_t MB = 1024 * 1024;
  u16*    hid_h = (u16*)(ws);
  u16*    hid_l = (u16*)(ws + 8 * MB);
  u16*    wq_h  = (u16*)(ws + 16 * MB);
  u16*    wq_l  = (u16*)(ws + 32 * MB);
  u16*    wo_h  = (u16*)(ws + 48 * MB);
  u16*    wo_l  = (u16*)(ws + 56 * MB);
  float*  qkv   = (float*)(ws + 64 * MB);
  u16*    q_h   = (u16*)(ws + 96 * MB);
  u16*    q_l   = (u16*)(ws + 104 * MB);
  u16*    k_h   = (u16*)(ws + 112 * MB);
  u16*    k_l   = (u16*)(ws + 116 * MB);
  u16*    v_h   = (u16*)(ws + 120 * MB);
  u16*    v_l   = (u16*)(ws + 124 * MB);
  u16*    at_h  = (u16*)(ws + 128 * MB);
  u16*    at_l  = (u16*)(ws + 136 * MB);
  float2* tab   = (float2*)(ws + 144 * MB);
  // flash partials overlay DEAD regions (wq_* dead after QKV GEMM, qkv dead
  // after normrope): Oph 3x8.39MB @16M, Mp @42M, Lp @43M, Opl @64M.
  u16*   Oph = (u16*)(ws + 16 * MB);
  float* Mp  = (float*)(ws + 42 * MB);
  float* Lp  = (float*)(ws + 43 * MB);
  u16*   Opl = (u16*)(ws + 64 * MB);

  k_trig<<<T, 64, 0, stream>>>(pos, tab);
  k_split<<<(T * C_HID) / 1024, 256, 0, stream>>>(hid, hid_h, hid_l, T * C_HID);
  k_split_tr<<<dim3(C_NQKV / 64, C_HID / 64), 256, 0, stream>>>(wqkv, wq_h, wq_l, C_HID, C_NQKV);
  k_split_tr<<<dim3(C_HID / 64, C_HID / 64), 256, 0, stream>>>(wo, wo_h, wo_l, C_HID, C_HID);
  k_gemm_x3<<<dim3(C_NQKV / 128, T / 128), 256, 0, stream>>>(
      hid_h, hid_l, wq_h, wq_l, qkv, T, C_NQKV, C_HID);
  k_normrope<<<(T * 32) / 4, 256, 0, stream>>>(qkv, tab, qnw, knw, q_h, q_l, k_h, k_l, v_h, v_l, T);
  k_flash<<<3 * T / 64 * C_NKV, 512, 0, stream>>>(q_h, q_l, k_h, k_l, v_h, v_l,
                                                  Oph, Opl, Mp, Lp, T);
  k_merge<<<(T * C_NH * 16) / 256, 256, 0, stream>>>(Oph, Opl, Mp, Lp, at_h, at_l, T);
  k_gemm_x3<<<dim3(C_HID / 128, T / 128), 256, 0, stream>>>(
      at_h, at_l, wo_h, wo_l, out, T, C_HID, C_HID);
}

// Round 9
// 495.886 us; speedup vs baseline: 1.1475x; 1.1475x over previous
//
#include <hip/hip_runtime.h>
#include <cstdint>
#include <cstddef>

// MossVLSelfAttention fused pipeline, MI355X round 9.
// Changes vs round 8:
//  - k_flash: EXACT revert to round 7 (gload_lds staging). Round 8's T14
//    reg-staging spilled stg[] to scratch (VGPR held at 64, +137MB HBM) -> 195us.
//  - k_gemm_x3: BK=64 (halved barrier count) + XOR chunk-swizzled LDS (flash's
//    proven pre-swizzled-global pattern; kills stride-64B ds_read conflicts).
//  - out-proj: split-K=2 via blockIdx.z -> private f32 buffers (NO atomics),
//    new k_add2 combines. Fixes 1 block/CU occupancy hole (~160us for 51.5GF).
//  - k_split / k_split_tr: short8-vectorized stores (G13).
// Precision: bf16x3 matmuls, fp32 softmax/accum, bf16x2 partial-O.
// Workspace (byte offsets, ~146 MB):
//   0   hid_hi[T][2048]      8M   hid_lo          (dead after QKV GEMM)
//   16M wqkvT_hi [+16M lo]                        (dead after QKV GEMM)
//     -> flash partials: Oph[3][T][16][128] @16M, Mp @42M, Lp @43M (dead after merge)
//     -> out-proj split-K: C0 @16M, C1 @32M (16MB each)
//   48M woT_hi   56M woT_lo                       (live until out-proj)
//   64M qkv_f32[T][4096]                          (dead after normrope)
//     -> flash partials: Opl[3][T][16][128] @64M  (dead after merge)
//   96M q_hi 104M q_lo 112M k_hi 116M k_lo 120M vT_hi 124M vT_lo
//   128M attn_hi 136M attn_lo 144M trig[T][64] float2

#define C_NH 16
#define C_NKV 8
#define C_DH 128
#define C_HID 2048
#define C_NQKV 4096
#define KVB 32

typedef unsigned short u16;
typedef __attribute__((ext_vector_type(8))) short short8;
typedef __attribute__((ext_vector_type(4))) float f32x4;

__device__ __forceinline__ u16 f2bf(float x) {
  uint32_t u = __float_as_uint(x);
  u += 0x7FFFu + ((u >> 16) & 1u);   // round-to-nearest-even
  return (u16)(u >> 16);
}
__device__ __forceinline__ float bf2f(u16 h) {
  return __uint_as_float(((uint32_t)h) << 16);
}
__device__ __forceinline__ void bsplit(float x, u16& hi, u16& lo) {
  u16 h = f2bf(x);
  hi = h;
  lo = f2bf(x - bf2f(h));             // residual: ~16 mantissa bits total
}

// async global->LDS, 16B/lane; LDS dest = wave-uniform base + lane*16.
__device__ __forceinline__ void gload16(const void* g, void* l) {
  __builtin_amdgcn_global_load_lds(
      (const __attribute__((address_space(1))) void*)g,
      (__attribute__((address_space(3))) void*)l, 16, 0, 0);
}

// ---------------- trig table ---------------------------------------------------
__global__ void k_trig(const int* __restrict__ pos, float2* __restrict__ tab) {
  int t = blockIdx.x;
  int j = threadIdx.x;                // 64 threads
  float inv = 1.0f / powf(1.0e6f, (float)j * (1.0f / 64.0f));
  float ang = (float)pos[t] * inv;
  tab[t * 64 + j] = make_float2(cosf(ang), sinf(ang));
}

// ---------------- plain split: f32[n] -> hi/lo bf16 (short8 stores) -----------
__global__ void k_split(const float* __restrict__ in, u16* __restrict__ hi,
                        u16* __restrict__ lo, int n) {
  int i = (blockIdx.x * 256 + threadIdx.x) * 8;
  if (i >= n) return;
  float4 x0 = *(const float4*)(in + i);
  float4 x1 = *(const float4*)(in + i + 4);
  short8 hv, lv;
  u16 h, l;
  bsplit(x0.x, h, l); hv[0] = (short)h; lv[0] = (short)l;
  bsplit(x0.y, h, l); hv[1] = (short)h; lv[1] = (short)l;
  bsplit(x0.z, h, l); hv[2] = (short)h; lv[2] = (short)l;
  bsplit(x0.w, h, l); hv[3] = (short)h; lv[3] = (short)l;
  bsplit(x1.x, h, l); hv[4] = (short)h; lv[4] = (short)l;
  bsplit(x1.y, h, l); hv[5] = (short)h; lv[5] = (short)l;
  bsplit(x1.z, h, l); hv[6] = (short)h; lv[6] = (short)l;
  bsplit(x1.w, h, l); hv[7] = (short)h; lv[7] = (short)l;
  *(short8*)(hi + i) = hv;
  *(short8*)(lo + i) = lv;
}

// ---------------- split + transpose: in[K][N] -> hi/lo[N][K] (short8 stores) --
__global__ void k_split_tr(const float* __restrict__ in, u16* __restrict__ hi,
                           u16* __restrict__ lo, int K, int N) {
  __shared__ float t[64][65];
  const int kb = blockIdx.y * 64, nb = blockIdx.x * 64;
  const int tid = threadIdx.x;
  for (int i = tid; i < 4096; i += 256) {
    int r = i >> 6, c = i & 63;
    t[r][c] = in[(size_t)(kb + r) * N + nb + c];
  }
  __syncthreads();
  for (int i = tid; i < 512; i += 256) {     // 512 short8 outputs
    int r = i >> 3, c0 = (i & 7) * 8;        // r = n-local, c0 = k-local base
    short8 hv, lv;
    u16 h, l;
#pragma unroll
    for (int j = 0; j < 8; ++j) {
      bsplit(t[c0 + j][r], h, l);
      hv[j] = (short)h;
      lv[j] = (short)l;
    }
    size_t o = (size_t)(nb + r) * K + kb + c0;
    *(short8*)(hi + o) = hv;
    *(short8*)(lo + o) = lv;
  }
}

// ---------------- bf16x3 GEMM: C[M][N] = A[M][K] * B^T[N][K] ------------------
// 128x128 tile, 4 waves, BK=64, single-buffer XOR-swizzled LDS staged via
// global_load_lds width=16 (pre-swizzled global src), 2 barriers per K-step.
// blockIdx.z = split-K slice; C_z = C + z*M*N (private buffers, no atomics).
__global__ __launch_bounds__(256, 2)
void k_gemm_x3(const u16* __restrict__ Ah, const u16* __restrict__ Al,
               const u16* __restrict__ Bh, const u16* __restrict__ Bl,
               float* __restrict__ C, int M, int N, int K, int klen) {
  __shared__ u16 lds[4][128 * 64];      // [Ah,Al,Bh,Bl][128 rows x 64 k] = 64KB
  const int tid = threadIdx.x;
  const int lane = tid & 63;
  const int wv = tid >> 6;
  const int wr = wv >> 1, wc = wv & 1;
  const int mb = blockIdx.y * 128, nb = blockIdx.x * 128;
  const int k0 = blockIdx.z * klen;
  float* Cz = C + (size_t)blockIdx.z * M * N;
  const int ra = lane & 15, lq = lane >> 4;

  f32x4 acc[4][4] = {};
  const int nk = klen >> 6;
  // staging geometry: 16 x 1KB loads per array; load L covers rows L*8..L*8+7,
  // lane supplies phys chunk (lane&7) of row L*8+(lane>>3); global src is the
  // LOGICAL chunk (lane&7)^(row&7)  (pre-swizzled source, m173 pattern).
  const int s_row = lane >> 3, s_pc = lane & 7;

  for (int kt = 0; kt < nk; ++kt) {
    const int kb = k0 + kt * 64;
    __syncthreads();                    // previous compute done, LDS reusable
#pragma unroll
    for (int ci = 0; ci < 4; ++ci) {    // wave stages loads wv*4+ci per array
      const int L = wv * 4 + ci;
      const int row = L * 8 + s_row;
      const int cl = s_pc ^ (row & 7);  // logical k-chunk for this lane
      gload16(Ah + (size_t)(mb + row) * K + kb + cl * 8, &lds[0][L * 512]);
      gload16(Al + (size_t)(mb + row) * K + kb + cl * 8, &lds[1][L * 512]);
      gload16(Bh + (size_t)(nb + row) * K + kb + cl * 8, &lds[2][L * 512]);
      gload16(Bl + (size_t)(nb + row) * K + kb + cl * 8, &lds[3][L * 512]);
    }
    __syncthreads();                    // drains vmcnt before barrier

#pragma unroll
    for (int kk = 0; kk < 2; ++kk) {    // two K=32 sub-steps per staged tile
      short8 a_h[4], a_l[4], b_h[4], b_l[4];
#pragma unroll
      for (int m = 0; m < 4; ++m) {
        int r = wr * 64 + m * 16 + ra;
        int off = r * 64 + ((kk * 4 + lq) ^ (r & 7)) * 8;
        a_h[m] = *(const short8*)&lds[0][off];
        a_l[m] = *(const short8*)&lds[1][off];
      }
#pragma unroll
      for (int n = 0; n < 4; ++n) {
        int r = wc * 64 + n * 16 + ra;
        int off = r * 64 + ((kk * 4 + lq) ^ (r & 7)) * 8;
        b_h[n] = *(const short8*)&lds[2][off];
        b_l[n] = *(const short8*)&lds[3][off];
      }
#pragma unroll
      for (int m = 0; m < 4; ++m)
#pragma unroll
        for (int n = 0; n < 4; ++n) {
          acc[m][n] = __builtin_amdgcn_mfma_f32_16x16x32_bf16(a_h[m], b_h[n], acc[m][n], 0, 0, 0);
          acc[m][n] = __builtin_amdgcn_mfma_f32_16x16x32_bf16(a_h[m], b_l[n], acc[m][n], 0, 0, 0);
          acc[m][n] = __builtin_amdgcn_mfma_f32_16x16x32_bf16(a_l[m], b_h[n], acc[m][n], 0, 0, 0);
        }
    }
  }
  const int cr = mb + wr * 64 + lq * 4;
  const int cc = nb + wc * 64 + ra;
#pragma unroll
  for (int m = 0; m < 4; ++m)
#pragma unroll
    for (int n = 0; n < 4; ++n)
#pragma unroll
      for (int r = 0; r < 4; ++r)
        Cz[(size_t)(cr + m * 16 + r) * N + cc + n * 16] = acc[m][n][r];
}

// ---------------- add split-K halves: out = C0 + C1 ---------------------------
__global__ void k_add2(const float* __restrict__ C0, const float* __restrict__ C1,
                       float* __restrict__ out, int n) {
  int i = (blockIdx.x * 256 + threadIdx.x) * 4;
  if (i >= n) return;
  float4 a = *(const float4*)(C0 + i);
  float4 b = *(const float4*)(C1 + i);
  a.x += b.x; a.y += b.y; a.z += b.z; a.w += b.w;
  *(float4*)(out + i) = a;
}

// ---------------- RMSNorm + RoPE + split (q,k) / split+transpose (v) ----------
__global__ void k_normrope(const float* __restrict__ qkv, const float2* __restrict__ tab,
                           const float* __restrict__ qw, const float* __restrict__ kw,
                           u16* __restrict__ Qh, u16* __restrict__ Ql,
                           u16* __restrict__ Kh, u16* __restrict__ Kl,
                           u16* __restrict__ Vh, u16* __restrict__ Vl, int T) {
  int gw = blockIdx.x * 4 + (threadIdx.x >> 6);
  if (gw >= T * 32) return;
  int lane = threadIdx.x & 63;
  int t = gw >> 5, hd = gw & 31;
  const float* src;
  if (hd < C_NH)              src = qkv + (size_t)t * C_NQKV + hd * C_DH;
  else if (hd < C_NH + C_NKV) src = qkv + (size_t)t * C_NQKV + C_NH * C_DH + (hd - C_NH) * C_DH;
  else                        src = qkv + (size_t)t * C_NQKV + (C_NH + C_NKV) * C_DH + (hd - C_NH - C_NKV) * C_DH;
  float x1 = src[lane], x2 = src[lane + 64];

  if (hd >= C_NH + C_NKV) {   // v: split + store transposed [8][128][T]
    int vh = hd - C_NH - C_NKV;
    u16 h, l;
    bsplit(x1, h, l);
    size_t o1 = ((size_t)vh * C_DH + lane) * T + t;
    Vh[o1] = h; Vl[o1] = l;
    bsplit(x2, h, l);
    size_t o2 = ((size_t)vh * C_DH + lane + 64) * T + t;
    Vh[o2] = h; Vl[o2] = l;
    return;
  }
  float ss = x1 * x1 + x2 * x2;
  ss += __shfl_xor(ss, 1, 64);
  ss += __shfl_xor(ss, 2, 64);
  ss += __shfl_xor(ss, 4, 64);
  ss += __shfl_xor(ss, 8, 64);
  ss += __shfl_xor(ss, 16, 64);
  ss += __shfl_xor(ss, 32, 64);
  float rms = rsqrtf(ss * (1.0f / 128.0f) + 1e-6f);
  const float* w = (hd < C_NH) ? qw : kw;
  float y1 = x1 * rms * w[lane];
  float y2 = x2 * rms * w[lane + 64];
  float2 cs = tab[t * 64 + lane];
  float o1 = y1 * cs.x - y2 * cs.y;
  float o2 = y2 * cs.x + y1 * cs.y;
  u16 h, l;
  if (hd < C_NH) {
    size_t o = ((size_t)t * C_NH + hd) * C_DH + lane;
    bsplit(o1, h, l); Qh[o] = h; Ql[o] = l;
    bsplit(o2, h, l); Qh[o + 64] = h; Ql[o + 64] = l;
  } else {
    int kh = hd - C_NH;
    size_t o = ((size_t)t * C_NKV + kh) * C_DH + lane;
    bsplit(o1, h, l); Kh[o] = h; Kl[o] = l;
    bsplit(o2, h, l); Kh[o + 64] = h; Kl[o + 64] = l;
  }
}

// ---------------- causal flash attention (round-7 version, unchanged) ---------
// Grid 768: hk = f&7 (XCD pin), qt = (f>>3)&31, ks = f>>8 in {0,1,2}.
// Block 512 thr / 8 waves; wave owns 16 q-rows of one of 2 GQA heads.
// KVB=32 single-buffered swizzled LDS tile staged via global_load_lds.
__global__ __launch_bounds__(512, 4)
void k_flash(const u16* __restrict__ Qh, const u16* __restrict__ Ql,
             const u16* __restrict__ Kg_h, const u16* __restrict__ Kg_l,
             const u16* __restrict__ Vg_h, const u16* __restrict__ Vg_l,
             u16* __restrict__ Oph, u16* __restrict__ Opl,
             float* __restrict__ Mp, float* __restrict__ Lp, int T) {
  __shared__ u16 KV[4][KVB * C_DH];      // [Kh,Kl,Vh,Vl] 32x128 each = 32 KiB
  __shared__ u16 Pex[8][2][16 * 36];     // per-wave P hi/lo, pad 36 = 18 KiB
  const int tid = threadIdx.x, lane = tid & 63, wv = tid >> 6;
  const int lm = lane & 15, lq = lane >> 4;
  const int f = blockIdx.x;
  const int hk = f & 7, qt = (f >> 3) & 31, ks = f >> 8;
  const int wq = wv & 3, wh = wv >> 2;
  const int h = hk * 2 + wh;
  const int row16 = qt * 64 + wq * 16;      // wave's 16-row base (global)

  // ---- Q fragments in registers for the whole kernel ----
  short8 qfh[4], qfl[4];
#pragma unroll
  for (int kc = 0; kc < 4; ++kc) {
    size_t o = ((size_t)(row16 + lm) * C_NH + h) * C_DH + kc * 32 + lq * 8;
    qfh[kc] = *(const short8*)(Qh + o);
    qfl[kc] = *(const short8*)(Ql + o);
  }
  f32x4 o_acc[8] = {};
  float m_r[4], l_r[4];
#pragma unroll
  for (int r = 0; r < 4; ++r) { m_r[r] = -1e30f; l_r[r] = 0.f; }

  // ---- staging: wave (wv>>1) owns array, (wv&1) owns 16-row half; 4x 1KB ----
  const int s_arr = wv >> 1, s_hf = wv & 1;
  const int s_rr = lane >> 4, s_ph = lane & 15;
  auto stage = [&](int kt) {
    const int kvb = kt * KVB;
#pragma unroll
    for (int j = 0; j < 4; ++j) {
      const int r0 = s_hf * 16 + j * 4;
      const int r = r0 + s_rr;
      const int c = s_ph ^ (r & 15);          // logical chunk (pre-swizzled src)
      const u16* g;
      if (s_arr < 2) {                         // K: [key][128] rows
        const u16* base = (s_arr == 0) ? Kg_h : Kg_l;
        g = base + ((size_t)(kvb + r) * C_NKV + hk) * C_DH + c * 8;
      } else {                                 // V: logical (r=d&31, c=(d>>5)*4+keychunk)
        const int d = r + ((c >> 2) << 5);
        const u16* base = (s_arr == 2) ? Vg_h : Vg_l;
        g = base + ((size_t)hk * C_DH + d) * T + kvb + (c & 3) * 8;
      }
      gload16(g, &KV[s_arr][r0 * C_DH]);
    }
  };

  const float scale = 0.08838834764831845f;   // 1/sqrt(128)
  const int nt32 = 2 * qt + 2;
  const int t0 = (ks * nt32) / 3, t1 = ((ks + 1) * nt32) / 3;

  for (int kt = t0; kt < t1; ++kt) {
    const int kvb = kt * KVB;
    stage(kt);
    __syncthreads();                          // staged tile visible

    // ---- S = Q K^T (swizzled LDS reads) ----
    f32x4 s[2] = {};
#pragma unroll
    for (int nt = 0; nt < 2; ++nt) {
      const int krow = nt * 16 + lm;
#pragma unroll
      for (int kc = 0; kc < 4; ++kc) {
        const int phys = (kc * 4 + lq) ^ lm;       // (row&15)==lm
        short8 bh = *(const short8*)&KV[0][krow * C_DH + phys * 8];
        short8 bl = *(const short8*)&KV[1][krow * C_DH + phys * 8];
        s[nt] = __builtin_amdgcn_mfma_f32_16x16x32_bf16(qfh[kc], bh, s[nt], 0, 0, 0);
        s[nt] = __builtin_amdgcn_mfma_f32_16x16x32_bf16(qfh[kc], bl, s[nt], 0, 0, 0);
        s[nt] = __builtin_amdgcn_mfma_f32_16x16x32_bf16(qfl[kc], bh, s[nt], 0, 0, 0);
      }
    }

    // ---- online softmax; `safe` guards fully-masked-first-tile (m=-1e30) ----
    float p[2][4];                                  // [nt][r]
#pragma unroll
    for (int r = 0; r < 4; ++r) {
      const int qrow = row16 + lq * 4 + r;
      float sv[2];
#pragma unroll
      for (int nt = 0; nt < 2; ++nt)
        sv[nt] = (kvb + nt * 16 + lm <= qrow) ? s[nt][r] * scale : -1e30f;
      float pm = fmaxf(sv[0], sv[1]);
      pm = fmaxf(pm, __shfl_xor(pm, 1, 16));
      pm = fmaxf(pm, __shfl_xor(pm, 2, 16));
      pm = fmaxf(pm, __shfl_xor(pm, 4, 16));
      pm = fmaxf(pm, __shfl_xor(pm, 8, 16));
      float mn = fmaxf(m_r[r], pm);
      const float safe = (mn <= -1e29f) ? 0.f : 1.f;
      float alpha = __expf(m_r[r] - mn);
      float ps = 0.f;
#pragma unroll
      for (int nt = 0; nt < 2; ++nt) {
        p[nt][r] = safe * __expf(sv[nt] - mn);
        ps += p[nt][r];
      }
      ps += __shfl_xor(ps, 1, 16);
      ps += __shfl_xor(ps, 2, 16);
      ps += __shfl_xor(ps, 4, 16);
      ps += __shfl_xor(ps, 8, 16);
      l_r[r] = l_r[r] * alpha + ps;
      m_r[r] = mn;
#pragma unroll
      for (int jb = 0; jb < 8; ++jb) o_acc[jb][r] *= alpha;
    }

    // ---- O += P V (K=32 over the whole tile; wave-local P exchange) ----
#pragma unroll
    for (int r = 0; r < 4; ++r)
#pragma unroll
      for (int t2 = 0; t2 < 2; ++t2) {
        u16 ph, pl;
        bsplit(p[t2][r], ph, pl);
        Pex[wv][0][(lq * 4 + r) * 36 + t2 * 16 + lm] = ph;
        Pex[wv][1][(lq * 4 + r) * 36 + t2 * 16 + lm] = pl;
      }
    short8 pah = *(const short8*)&Pex[wv][0][lm * 36 + lq * 8];
    short8 pal = *(const short8*)&Pex[wv][1][lm * 36 + lq * 8];
#pragma unroll
    for (int jb = 0; jb < 8; ++jb) {
      const int vrow = (jb & 1) * 16 + lm;               // = d & 31
      const int phys = ((jb >> 1) * 4 + lq) ^ lm;        // chunk ^ (row&15)
      const int roff = vrow * C_DH + phys * 8;
      short8 vh = *(const short8*)&KV[2][roff];
      short8 vl = *(const short8*)&KV[3][roff];
      o_acc[jb] = __builtin_amdgcn_mfma_f32_16x16x32_bf16(pah, vh, o_acc[jb], 0, 0, 0);
      o_acc[jb] = __builtin_amdgcn_mfma_f32_16x16x32_bf16(pah, vl, o_acc[jb], 0, 0, 0);
      o_acc[jb] = __builtin_amdgcn_mfma_f32_16x16x32_bf16(pal, vh, o_acc[jb], 0, 0, 0);
    }
    __syncthreads();                          // all reads done; next stage may overwrite
  }

  // ---- partial write: unnormalized O (bf16 hi/lo) + per-row stats ----
  const int S = T * C_NH;
#pragma unroll
  for (int r = 0; r < 4; ++r) {
    const int qrow = row16 + lq * 4 + r;
    const int rh = qrow * C_NH + h;
    if (lm == 0) { Mp[ks * S + rh] = m_r[r]; Lp[ks * S + rh] = l_r[r]; }
#pragma unroll
    for (int jb = 0; jb < 8; ++jb) {
      u16 hh, ll;
      bsplit(o_acc[jb][r], hh, ll);
      size_t oo = ((size_t)ks * S + rh) * C_DH + jb * 16 + lm;
      Oph[oo] = hh;
      Opl[oo] = ll;
    }
  }
}

// ---------------- merge 3 key-split partials -> bf16 hi/lo attn ---------------
__global__ void k_merge(const u16* __restrict__ Oph, const u16* __restrict__ Opl,
                        const float* __restrict__ Mp, const float* __restrict__ Lp,
                        u16* __restrict__ Oh, u16* __restrict__ Ol, int T) {
  const int idx = blockIdx.x * 256 + threadIdx.x;   // T*NH*16 total
  const int rh = idx >> 4, dg = idx & 15;
  const int S = T * C_NH;
  float m0 = Mp[rh], m1 = Mp[S + rh], m2 = Mp[2 * S + rh];
  float M = fmaxf(fmaxf(m0, m1), m2);
  float w0 = __expf(m0 - M), w1 = __expf(m1 - M), w2 = __expf(m2 - M);
  float L = w0 * Lp[rh] + w1 * Lp[S + rh] + w2 * Lp[2 * S + rh];
  float inv = 1.0f / L;
  const size_t b = (size_t)rh * C_DH + dg * 8;
  const size_t SO = (size_t)S * C_DH;
  short8 h0 = *(const short8*)(Oph + b),      l0 = *(const short8*)(Opl + b);
  short8 h1 = *(const short8*)(Oph + SO + b), l1 = *(const short8*)(Opl + SO + b);
  short8 h2 = *(const short8*)(Oph + 2 * SO + b), l2 = *(const short8*)(Opl + 2 * SO + b);
  short8 oh, ol;
#pragma unroll
  for (int j = 0; j < 8; ++j) {
    float o = w0 * (bf2f((u16)h0[j]) + bf2f((u16)l0[j]))
            + w1 * (bf2f((u16)h1[j]) + bf2f((u16)l1[j]))
            + w2 * (bf2f((u16)h2[j]) + bf2f((u16)l2[j]));
    u16 hh, ll;
    bsplit(o * inv, hh, ll);
    oh[j] = (short)hh;
    ol[j] = (short)ll;
  }
  *(short8*)(Oh + b) = oh;
  *(short8*)(Ol + b) = ol;
}

// ---------------- launch --------------------------------------------------------
extern "C" void kernel_launch(void* const* d_in, const int* in_sizes, int n_in,
                              void* d_out, int out_size, void* d_ws, size_t ws_size,
                              hipStream_t stream) {
  const int*   pos  = (const int*)d_in[0];
  const float* hid  = (const float*)d_in[1];
  const float* wqkv = (const float*)d_in[2];
  const float* qnw  = (const float*)d_in[3];
  const float* knw  = (const float*)d_in[4];
  const float* wo   = (const float*)d_in[5];
  float* out = (float*)d_out;
  const int T = in_sizes[0];                   // 2048

  char* ws = (char*)d_ws;
  const size_t MB = 1024 * 1024;
  u16*    hid_h = (u16*)(ws);
  u16*    hid_l = (u16*)(ws + 8 * MB);
  u16*    wq_h  = (u16*)(ws + 16 * MB);
  u16*    wq_l  = (u16*)(ws + 32 * MB);
  u16*    wo_h  = (u16*)(ws + 48 * MB);
  u16*    wo_l  = (u16*)(ws + 56 * MB);
  float*  qkv   = (float*)(ws + 64 * MB);
  u16*    q_h   = (u16*)(ws + 96 * MB);
  u16*    q_l   = (u16*)(ws + 104 * MB);
  u16*    k_h   = (u16*)(ws + 112 * MB);
  u16*    k_l   = (u16*)(ws + 116 * MB);
  u16*    v_h   = (u16*)(ws + 120 * MB);
  u16*    v_l   = (u16*)(ws + 124 * MB);
  u16*    at_h  = (u16*)(ws + 128 * MB);
  u16*    at_l  = (u16*)(ws + 136 * MB);
  float2* tab   = (float2*)(ws + 144 * MB);
  // flash partials overlay DEAD regions (wq_* dead after QKV GEMM, qkv dead
  // after normrope): Oph 3x8.39MB @16M, Mp @42M, Lp @43M, Opl @64M.
  u16*   Oph = (u16*)(ws + 16 * MB);
  float* Mp  = (float*)(ws + 42 * MB);
  float* Lp  = (float*)(ws + 43 * MB);
  u16*   Opl = (u16*)(ws + 64 * MB);
  // out-proj split-K buffers (regions dead after k_merge): C0 @16M, C1 @32M.
  float* Csp = (float*)(ws + 16 * MB);

  k_trig<<<T, 64, 0, stream>>>(pos, tab);
  k_split<<<(T * C_HID) / 2048, 256, 0, stream>>>(hid, hid_h, hid_l, T * C_HID);
  k_split_tr<<<dim3(C_NQKV / 64, C_HID / 64), 256, 0, stream>>>(wqkv, wq_h, wq_l, C_HID, C_NQKV);
  k_split_tr<<<dim3(C_HID / 64, C_HID / 64), 256, 0, stream>>>(wo, wo_h, wo_l, C_HID, C_HID);
  // QKV: M=2048 N=4096 K=2048, no split-K (512 blocks = 2/CU)
  k_gemm_x3<<<dim3(C_NQKV / 128, T / 128, 1), 256, 0, stream>>>(
      hid_h, hid_l, wq_h, wq_l, qkv, T, C_NQKV, C_HID, C_HID);
  k_normrope<<<(T * 32) / 4, 256, 0, stream>>>(qkv, tab, qnw, knw, q_h, q_l, k_h, k_l, v_h, v_l, T);
  k_flash<<<3 * T / 64 * C_NKV, 512, 0, stream>>>(q_h, q_l, k_h, k_l, v_h, v_l,
                                                  Oph, Opl, Mp, Lp, T);
  k_merge<<<(T * C_NH * 16) / 256, 256, 0, stream>>>(Oph, Opl, Mp, Lp, at_h, at_l, T);
  // out-proj: M=2048 N=2048 K=2048, split-K=2 -> 512 blocks = 2/CU, no atomics
  k_gemm_x3<<<dim3(C_HID / 128, T / 128, 2), 256, 0, stream>>>(
      at_h, at_l, wo_h, wo_l, Csp, T, C_HID, C_HID, C_HID / 2);
  k_add2<<<(T * C_HID) / 1024, 256, 0, stream>>>(Csp, Csp + (size_t)T * C_HID, out, T * C_HID);
}